// Round 1
// baseline (245.596 us; speedup 1.0000x reference)
//
#include <hip/hip_runtime.h>

// InnocentAttention: B=4 H=16 S=2048 D=64, fp32 in/out, per-batch event_length mask.
// Flash-style fwd, bf16 MFMA 16x16x32, S^T orientation (A=K, B=Q^T) so that
//  - softmax stats = per-lane reduce + 2 shuffles
//  - P^T packs into b64 LDS writes (1 per 16x16 tile)
//  - PV as O^T = V^T * P^T with all-b128 LDS frag reads
//  - output stores are float4-coalesced.

#define SQ 2048
#define DH 64
#define NBH 64          // B*H
#define TQ 128          // queries per block (4 waves x 32)
#define TQW 32          // queries per wave (2 n-tiles of 16)
#define TK 64           // keys per K-tile
#define LDK 72          // padded LDS strides (+8 bf16) to break bank aliasing
#define LDV 72
#define LDP 72

typedef __attribute__((ext_vector_type(4))) float f32x4;
typedef __attribute__((ext_vector_type(8))) short bf16x8;
typedef __attribute__((ext_vector_type(4))) short bf16x4;

__device__ __forceinline__ short bf16r(float x) {
    // round-to-nearest-even fp32 -> bf16
    union { float f; unsigned int u; } t; t.f = x;
    unsigned int r = t.u + 0x7fffu + ((t.u >> 16) & 1u);
    return (short)(r >> 16);
}

__device__ __forceinline__ unsigned int bf16pk(float lo, float hi) {
    return ((unsigned int)(unsigned short)bf16r(lo)) |
           (((unsigned int)(unsigned short)bf16r(hi)) << 16);
}

// ---- pre-pass: meanv[bh][d] = (1/S) * sum_j V[bh][j][d]  (for rows s >= el) ----
__global__ __launch_bounds__(256)
void meanv_partial(const float* __restrict__ V, float* __restrict__ MV) {
    const int bh  = blockIdx.x >> 4;
    const int seg = blockIdx.x & 15;            // 128 rows per block
    const float* vp = V + ((size_t)bh * SQ + (size_t)seg * 128) * DH;
    const int c  = threadIdx.x & 15;            // d4 group
    const int jr = threadIdx.x >> 4;            // 0..15
    f32x4 s = {0.f, 0.f, 0.f, 0.f};
    #pragma unroll
    for (int i = 0; i < 8; ++i) {
        f32x4 t = *(const f32x4*)(vp + (size_t)(jr + i * 16) * DH + c * 4);
        s += t;
    }
    __shared__ f32x4 red[16][16];
    red[jr][c] = s;
    __syncthreads();
    if (threadIdx.x < 16) {
        f32x4 t = red[0][threadIdx.x];
        #pragma unroll
        for (int j = 1; j < 16; ++j) t += red[j][threadIdx.x];
        const float s1 = 1.0f / (float)SQ;
        atomicAdd(&MV[bh * DH + threadIdx.x * 4 + 0], t[0] * s1);
        atomicAdd(&MV[bh * DH + threadIdx.x * 4 + 1], t[1] * s1);
        atomicAdd(&MV[bh * DH + threadIdx.x * 4 + 2], t[2] * s1);
        atomicAdd(&MV[bh * DH + threadIdx.x * 4 + 3], t[3] * s1);
    }
}

// ---- main flash kernel ----
__global__ __launch_bounds__(256, 2)
void flash_fwd(const float* __restrict__ Q, const float* __restrict__ K,
               const float* __restrict__ V, const int* __restrict__ EL,
               const float* __restrict__ MV, float* __restrict__ O) {
    const int bh    = blockIdx.x & (NBH - 1);   // bh fastest => same-bh blocks share XCD
    const int qt    = blockIdx.x >> 6;
    const int b     = bh >> 4;
    const int el    = EL[b];
    const int qbase = qt * TQ;

    const size_t base = (size_t)bh * SQ * DH;
    const float* Qp = Q + base;
    const float* Kp = K + base;
    const float* Vp = V + base;
    float* Op = O + base;

    const int tid = threadIdx.x;

    if (qbase >= el) {
        // whole tile invalid -> every row gets mean(V)
        const int c16 = tid & 15;
        const int r0  = tid >> 4;
        f32x4 mv = *(const f32x4*)(MV + bh * DH + c16 * 4);
        #pragma unroll
        for (int i = 0; i < 8; ++i) {
            const int row = qbase + r0 + i * 16;
            *(f32x4*)(Op + (size_t)row * DH + c16 * 4) = mv;
        }
        return;
    }

    const int wq   = tid >> 6;    // wave id 0..3
    const int lane = tid & 63;
    const int qd   = lane >> 4;   // quad 0..3
    const int c    = lane & 15;

    __shared__ short Kb[TK][LDK];        // K tile  [key][d]      (bf16)
    __shared__ short Vt[DH][LDV];        // V tile  [d][key]      (bf16, transposed)
    __shared__ short Pl[4][TQW][LDP];    // per-wave P [query][key] (bf16)

    // Q fragments (B-operand of S^T = K*Q^T), scale 1/sqrt(D) * log2(e) folded in.
    const float sc = 0.125f * 1.44269504f;
    bf16x8 qf[2][2];
    #pragma unroll
    for (int nt = 0; nt < 2; ++nt) {
        const int row = qbase + wq * TQW + nt * 16 + c;
        #pragma unroll
        for (int kc = 0; kc < 2; ++kc) {
            const float* p = Qp + (size_t)row * DH + kc * 32 + qd * 8;
            f32x4 a  = *(const f32x4*)p;
            f32x4 bb = *(const f32x4*)(p + 4);
            bf16x8 f;
            f[0] = bf16r(a[0] * sc);  f[1] = bf16r(a[1] * sc);
            f[2] = bf16r(a[2] * sc);  f[3] = bf16r(a[3] * sc);
            f[4] = bf16r(bb[0] * sc); f[5] = bf16r(bb[1] * sc);
            f[6] = bf16r(bb[2] * sc); f[7] = bf16r(bb[3] * sc);
            qf[nt][kc] = f;
        }
    }

    float m_[2] = {-1e30f, -1e30f};
    float l_[2] = {0.f, 0.f};
    f32x4 oacc[4][2];
    #pragma unroll
    for (int dt = 0; dt < 4; ++dt)
        #pragma unroll
        for (int nt = 0; nt < 2; ++nt)
            oacc[dt][nt] = (f32x4){0.f, 0.f, 0.f, 0.f};

    // staging index maps
    const int ksrow = tid >> 2;   // K: row 0..63
    const int ksdc  = tid & 3;    // K: 16-float chunk
    const int vpair = tid & 31;   // V: key pair (2*vpair, 2*vpair+1)
    const int vdg   = tid >> 5;   // V: 8-d group 0..7

    const int nkt = (el + TK - 1) / TK;
    for (int kt = 0; kt < nkt; ++kt) {
        const int k0 = kt * TK;

        // global loads (before barrier; held in regs across it)
        const float* kp = Kp + (size_t)(k0 + ksrow) * DH + ksdc * 16;
        f32x4 kg0 = *(const f32x4*)kp;
        f32x4 kg1 = *(const f32x4*)(kp + 4);
        f32x4 kg2 = *(const f32x4*)(kp + 8);
        f32x4 kg3 = *(const f32x4*)(kp + 12);
        const float* vp0 = Vp + (size_t)(k0 + 2 * vpair) * DH + vdg * 8;
        f32x4 vg0 = *(const f32x4*)vp0;
        f32x4 vg1 = *(const f32x4*)(vp0 + 4);
        f32x4 vg2 = *(const f32x4*)(vp0 + DH);
        f32x4 vg3 = *(const f32x4*)(vp0 + DH + 4);

        __syncthreads();  // previous tile's readers done

        {   // K tile, natural layout, 2x ds_write_b128
            bf16x8 w0, w1;
            w0[0] = bf16r(kg0[0]); w0[1] = bf16r(kg0[1]); w0[2] = bf16r(kg0[2]); w0[3] = bf16r(kg0[3]);
            w0[4] = bf16r(kg1[0]); w0[5] = bf16r(kg1[1]); w0[6] = bf16r(kg1[2]); w0[7] = bf16r(kg1[3]);
            w1[0] = bf16r(kg2[0]); w1[1] = bf16r(kg2[1]); w1[2] = bf16r(kg2[2]); w1[3] = bf16r(kg2[3]);
            w1[4] = bf16r(kg3[0]); w1[5] = bf16r(kg3[1]); w1[6] = bf16r(kg3[2]); w1[7] = bf16r(kg3[3]);
            *(bf16x8*)&Kb[ksrow][ksdc * 16]     = w0;
            *(bf16x8*)&Kb[ksrow][ksdc * 16 + 8] = w1;
        }
        {   // V tile transposed: pack key-pairs -> b32 writes (2-way bank alias = free)
            #pragma unroll
            for (int i = 0; i < 4; ++i) {
                *(unsigned int*)&Vt[vdg * 8 + i][2 * vpair]     = bf16pk(vg0[i], vg2[i]);
                *(unsigned int*)&Vt[vdg * 8 + 4 + i][2 * vpair] = bf16pk(vg1[i], vg3[i]);
            }
        }
        __syncthreads();  // tile visible

        // S^T = K * Q^T : tiles [mt=key16][nt=query16]
        f32x4 st[4][2];
        #pragma unroll
        for (int mt = 0; mt < 4; ++mt) {
            bf16x8 a0 = *(const bf16x8*)&Kb[mt * 16 + c][qd * 8];
            bf16x8 a1 = *(const bf16x8*)&Kb[mt * 16 + c][32 + qd * 8];
            #pragma unroll
            for (int nt = 0; nt < 2; ++nt) {
                f32x4 acc = (f32x4){0.f, 0.f, 0.f, 0.f};
                acc = __builtin_amdgcn_mfma_f32_16x16x32_bf16(a0, qf[nt][0], acc, 0, 0, 0);
                acc = __builtin_amdgcn_mfma_f32_16x16x32_bf16(a1, qf[nt][1], acc, 0, 0, 0);
                st[mt][nt] = acc;
            }
        }

        // key mask (only on the straddling tile; wave-uniform branch)
        if (k0 + TK > el) {
            #pragma unroll
            for (int mt = 0; mt < 4; ++mt)
                #pragma unroll
                for (int r = 0; r < 4; ++r) {
                    const int key = k0 + mt * 16 + qd * 4 + r;
                    if (key >= el) { st[mt][0][r] = -1e30f; st[mt][1][r] = -1e30f; }
                }
        }

        // online softmax (per query column; scores already in log2 domain)
        #pragma unroll
        for (int nt = 0; nt < 2; ++nt) {
            float tm = st[0][nt][0];
            #pragma unroll
            for (int mt = 0; mt < 4; ++mt)
                #pragma unroll
                for (int r = 0; r < 4; ++r)
                    tm = fmaxf(tm, st[mt][nt][r]);
            tm = fmaxf(tm, __shfl_xor(tm, 16));
            tm = fmaxf(tm, __shfl_xor(tm, 32));
            const float mn    = fmaxf(m_[nt], tm);
            const float alpha = exp2f(m_[nt] - mn);
            m_[nt] = mn;
            float rs = 0.f;
            #pragma unroll
            for (int mt = 0; mt < 4; ++mt)
                #pragma unroll
                for (int r = 0; r < 4; ++r) {
                    const float p = exp2f(st[mt][nt][r] - mn);
                    st[mt][nt][r] = p;
                    rs += p;
                }
            rs += __shfl_xor(rs, 16);
            rs += __shfl_xor(rs, 32);
            l_[nt] = l_[nt] * alpha + rs;
            #pragma unroll
            for (int dt = 0; dt < 4; ++dt) {
                oacc[dt][nt][0] *= alpha; oacc[dt][nt][1] *= alpha;
                oacc[dt][nt][2] *= alpha; oacc[dt][nt][3] *= alpha;
            }
        }

        // P -> LDS [query][key]: 4 consecutive keys per lane => one b64 write per tile
        #pragma unroll
        for (int nt = 0; nt < 2; ++nt)
            #pragma unroll
            for (int mt = 0; mt < 4; ++mt) {
                bf16x4 pk;
                pk[0] = bf16r(st[mt][nt][0]);
                pk[1] = bf16r(st[mt][nt][1]);
                pk[2] = bf16r(st[mt][nt][2]);
                pk[3] = bf16r(st[mt][nt][3]);
                *(bf16x4*)&Pl[wq][nt * 16 + c][mt * 16 + qd * 4] = pk;
            }

        // O^T += V^T * P^T  (A from Vt, B from Pl — all ds_read_b128)
        #pragma unroll
        for (int kc = 0; kc < 2; ++kc) {
            bf16x8 pb0 = *(const bf16x8*)&Pl[wq][c][kc * 32 + qd * 8];
            bf16x8 pb1 = *(const bf16x8*)&Pl[wq][16 + c][kc * 32 + qd * 8];
            #pragma unroll
            for (int dt = 0; dt < 4; ++dt) {
                bf16x8 vf = *(const bf16x8*)&Vt[dt * 16 + c][kc * 32 + qd * 8];
                oacc[dt][0] = __builtin_amdgcn_mfma_f32_16x16x32_bf16(vf, pb0, oacc[dt][0], 0, 0, 0);
                oacc[dt][1] = __builtin_amdgcn_mfma_f32_16x16x32_bf16(vf, pb1, oacc[dt][1], 0, 0, 0);
            }
        }
    }

    // epilogue: normalize + store (float4, d-contiguous); invalid rows -> meanv
    #pragma unroll
    for (int nt = 0; nt < 2; ++nt) {
        const int row = qbase + wq * TQW + nt * 16 + c;
        if (row < el) {
            const float inv = 1.0f / l_[nt];
            #pragma unroll
            for (int dt = 0; dt < 4; ++dt) {
                f32x4 o = oacc[dt][nt];
                o[0] *= inv; o[1] *= inv; o[2] *= inv; o[3] *= inv;
                *(f32x4*)(Op + (size_t)row * DH + dt * 16 + qd * 4) = o;
            }
        } else {
            #pragma unroll
            for (int dt = 0; dt < 4; ++dt) {
                f32x4 mv = *(const f32x4*)(MV + bh * DH + dt * 16 + qd * 4);
                *(f32x4*)(Op + (size_t)row * DH + dt * 16 + qd * 4) = mv;
            }
        }
    }
}

extern "C" void kernel_launch(void* const* d_in, const int* in_sizes, int n_in,
                              void* d_out, int out_size, void* d_ws, size_t ws_size,
                              hipStream_t stream) {
    const float* q  = (const float*)d_in[0];
    const float* k  = (const float*)d_in[1];
    const float* v  = (const float*)d_in[2];
    const int*   el = (const int*)d_in[3];
    float* out = (float*)d_out;
    float* mv  = (float*)d_ws;   // NBH*DH fp32 = 16 KB

    hipMemsetAsync(mv, 0, NBH * DH * sizeof(float), stream);
    meanv_partial<<<dim3(NBH * 16), dim3(256), 0, stream>>>(v, mv);
    flash_fwd<<<dim3(NBH * (SQ / TQ)), dim3(256), 0, stream>>>(q, k, v, el, mv, out);
}